// Round 14
// baseline (739.579 us; speedup 1.0000x reference)
//
#include <hip/hip_runtime.h>

constexpr int Lx = 8;
constexpr int Bx = 16;
constexpr int Dx = 512;
constexpr int Sx = 1500;
constexpr int Ex = 8;
constexpr int Kx = 1024;
constexpr int BS = Bx * Sx;          // 24000
#define EPSF 1e-12f

// barrier that drains LDS ops only -- global stores stay in flight (m201 pattern)
__device__ __forceinline__ void lds_barrier() {
    asm volatile("s_waitcnt lgkmcnt(0)" ::: "memory");
    __builtin_amdgcn_s_barrier();
    asm volatile("" ::: "memory");
}

// -------- precompute: WiT[l][d][e] = (g*v/||v||)(e,d) transposed, norm over D --------
__global__ __launch_bounds__(64) void k_wn_in(const float* __restrict__ v,
                                              const float* __restrict__ g,
                                              float* __restrict__ WiT) {
    int row = blockIdx.x;            // l*E + e
    int l = row >> 3, e = row & 7;
    int lane = threadIdx.x;          // 0..63
    const float* vr = v + row * Dx;
    float s = 0.f;
    for (int j = lane; j < Dx; j += 64) { float t = vr[j]; s += t * t; }
    for (int off = 32; off; off >>= 1) s += __shfl_down(s, off);
    s = __shfl(s, 0);
    float scale = g[row] / sqrtf(s);
    for (int j = lane; j < Dx; j += 64)
        WiT[((size_t)l * Dx + j) * Ex + e] = vr[j] * scale;
}

// ------ precompute: Wo[l][d][e] (norm over E), cn = l2norm(cb), cc = sum(cn^2) -------
__global__ __launch_bounds__(256) void k_wn_out_cb(const float* __restrict__ ov,
                                                   const float* __restrict__ og,
                                                   const float* __restrict__ cb,
                                                   float* __restrict__ Wo,
                                                   float* __restrict__ cn,
                                                   float* __restrict__ cc,
                                                   double* __restrict__ acc) {
    int r = blockIdx.x * blockDim.x + threadIdx.x;
    if (r == 0) *acc = 0.0;
    if (r < Lx * Dx) {
        const float* vr = ov + r * Ex;
        float s = 0.f;
        #pragma unroll
        for (int e = 0; e < Ex; e++) s += vr[e] * vr[e];
        float sc = og[r] / sqrtf(s);
        #pragma unroll
        for (int e = 0; e < Ex; e++) Wo[r * Ex + e] = vr[e] * sc;
    } else {
        int q = r - Lx * Dx;
        if (q < Lx * Kx) {
            const float* vr = cb + q * Ex;
            float s = 0.f;
            #pragma unroll
            for (int e = 0; e < Ex; e++) s += vr[e] * vr[e];
            float n = fmaxf(sqrtf(s), EPSF);
            float s2 = 0.f, qv[Ex];
            #pragma unroll
            for (int e = 0; e < Ex; e++) { qv[e] = vr[e] / n; s2 += qv[e] * qv[e]; }
            #pragma unroll
            for (int e = 0; e < Ex; e++) cn[q * Ex + e] = qv[e];
            cc[q] = s2;
        }
    }
}

// ---------------------------- the fused 8-layer pipeline -----------------------------
// block = 256 threads = 32 columns x 8 d-groups. Each thread holds xr[d] for
// d = g*64 + i (i=0..63) of its column in registers across all layers.
// VQ: single 8-column pass per wave -- each LDS code-read amortized over 8 dots.
__global__ __launch_bounds__(256, 3) void k_mega(const float* __restrict__ x,
                                                 const float* __restrict__ WiT,
                                                 const float* __restrict__ ibias,
                                                 const float* __restrict__ Wo,
                                                 const float* __restrict__ obias,
                                                 const float* __restrict__ cb,
                                                 const float* __restrict__ cn,
                                                 const float* __restrict__ cc,
                                                 float* __restrict__ out0,
                                                 float* __restrict__ oidx,
                                                 float* __restrict__ logits,
                                                 double* __restrict__ acc) {
    __shared__ float4 cnA[Kx];            // 16 KB  codes e0..3 (contiguous: conflict-free)
    __shared__ float4 cnB[Kx];            // 16 KB  codes e4..7
    __shared__ float  ccs[Kx];            // 4 KB
    __shared__ float  red[8 * Ex * 32];   // 8 KB proj partials [g][e][col]
    __shared__ float  xprojs[Ex * 32];    // 1 KB  [e][col]
    __shared__ float  xqs[Ex * 32];       // 1 KB  [e][col]
    __shared__ float  bred[4];

    const int t = threadIdx.x;
    const int col = t & 31;
    const int g = t >> 5;
    const int wave = t >> 6, lane = t & 63;
    const int c = blockIdx.x * 32 + col;       // global column 0..23999
    const int b = c / Sx;
    const int s = c - b * Sx;
    const float* xcol = x + (size_t)b * Dx * Sx + s;

    float xr[64];
    #pragma unroll
    for (int i = 0; i < 64; i++) xr[i] = xcol[(size_t)(g * 64 + i) * Sx];

    float lossp = 0.f;

    for (int l = 0; l < Lx; l++) {
        // ---- issue codebook loads into regs (consumed after proj; hides latency) ----
        const float4* cn4 = (const float4*)(cn + (size_t)l * Kx * Ex);
        const float4* cc4 = (const float4*)(cc + l * Kx);
        float4 ra[4], rb[4], rc;
        #pragma unroll
        for (int q = 0; q < 4; q++) {
            ra[q] = cn4[(t + 256 * q) * 2];
            rb[q] = cn4[(t + 256 * q) * 2 + 1];
        }
        rc = cc4[t];

        // ---- proj partials: pacc[e] = sum_{d in mine} WiT[d][e] * xr[d] ----
        const float4* wt = (const float4*)(WiT + (size_t)l * Dx * Ex);
        float pacc[8] = {0, 0, 0, 0, 0, 0, 0, 0};
        #pragma unroll
        for (int i = 0; i < 64; i++) {
            int d = g * 64 + i;
            float4 w0 = wt[d * 2 + 0];
            float4 w1 = wt[d * 2 + 1];
            float v = xr[i];
            pacc[0] += w0.x * v; pacc[1] += w0.y * v;
            pacc[2] += w0.z * v; pacc[3] += w0.w * v;
            pacc[4] += w1.x * v; pacc[5] += w1.y * v;
            pacc[6] += w1.z * v; pacc[7] += w1.w * v;
        }
        #pragma unroll
        for (int e = 0; e < 8; e++) red[(g * 8 + e) * 32 + col] = pacc[e];

        // ---- write staged codebook to LDS (prev layer's VQ reads done: S3) ----
        #pragma unroll
        for (int q = 0; q < 4; q++) {
            cnA[t + 256 * q] = ra[q];
            cnB[t + 256 * q] = rb[q];
        }
        *(float4*)&ccs[t * 4] = rc;
        lds_barrier();                                     // S1: red + codebook ready

        // ---- finalize x_proj: thread (col, e=g) sums 8 partials + bias ----
        {
            float sum = 0.f;
            #pragma unroll
            for (int gg = 0; gg < 8; gg++) sum += red[(gg * 8 + g) * 32 + col];
            xprojs[g * 32 + col] = sum + ibias[l * Ex + g];
        }
        lds_barrier();                                     // S2: xprojs ready

        // ---- VQ: wave owns cols wave*8..wave*8+7; ONE 8-column pass ----
        {
            float xn2[8][8];                 // 2*xn (exact scaling; dot2 == 2*dot bitwise)
            float xc[8], best[8];
            int bk[8];
            float* lrow0 = logits + ((size_t)(blockIdx.x * 32 + wave * 8) * Lx + l) * Kx;
            #pragma unroll
            for (int c8 = 0; c8 < 8; c8++) {
                int mycol = wave * 8 + c8;
                float xp[8]; float xx2 = 0.f;
                #pragma unroll
                for (int e = 0; e < 8; e++) {
                    xp[e] = xprojs[e * 32 + mycol];
                    xx2 += xp[e] * xp[e];
                }
                float nrm = fmaxf(sqrtf(xx2), EPSF);
                float xx = 0.f;
                #pragma unroll
                for (int e = 0; e < 8; e++) {
                    float xnv = xp[e] / nrm;
                    xx += xnv * xnv;
                    xn2[c8][e] = 2.f * xnv;
                }
                xc[c8] = xx;
                best[c8] = -3.0e38f;
                bk[c8] = 0;
            }
            #pragma unroll 2
            for (int j = 0; j < 16; j++) {
                int k = j * 64 + lane;
                float4 a  = cnA[k];
                float4 b4 = cnB[k];
                float  cv = ccs[k];
                #pragma unroll
                for (int c8 = 0; c8 < 8; c8++) {
                    float dot2 = xn2[c8][0] * a.x  + xn2[c8][1] * a.y +
                                 xn2[c8][2] * a.z  + xn2[c8][3] * a.w +
                                 xn2[c8][4] * b4.x + xn2[c8][5] * b4.y +
                                 xn2[c8][6] * b4.z + xn2[c8][7] * b4.w;
                    float lg = -(xc[c8] - dot2 + cv);
                    lrow0[(size_t)c8 * (Lx * Kx) + k] = lg;
                    if (lg > best[c8]) { best[c8] = lg; bk[c8] = k; }
                }
            }
            #pragma unroll
            for (int c8 = 0; c8 < 8; c8++) {
                float bv = best[c8]; int bi = bk[c8];
                for (int off = 32; off; off >>= 1) {   // argmax, np tie-break
                    float ov = __shfl_xor(bv, off);
                    int   oi = __shfl_xor(bi, off);
                    if (ov > bv || (ov == bv && oi < bi)) { bv = ov; bi = oi; }
                }
                int mycol = wave * 8 + c8;
                int mc = blockIdx.x * 32 + mycol;
                int mb = mc / Sx, ms = mc - mb * Sx;
                if (lane == 0) oidx[((size_t)mb * Lx + l) * Sx + ms] = (float)bi;
                if (lane < 8) {
                    float q = cb[((size_t)l * Kx + bi) * Ex + lane];
                    xqs[lane * 32 + mycol] = q;
                    float dl = xprojs[lane * 32 + mycol] - q;
                    lossp += dl * dl;
                }
            }
        }
        lds_barrier();                                     // S3: xqs ready, VQ reads done

        // ---- residual update: xr[d] -= Wo[d][:] . xq + ob[d] ----
        float xq[8];
        #pragma unroll
        for (int e = 0; e < 8; e++) xq[e] = xqs[e * 32 + col];
        const float4* wo4 = (const float4*)(Wo + (size_t)l * Dx * Ex);
        const float* obl = obias + l * Dx;
        #pragma unroll
        for (int i = 0; i < 64; i++) {
            int d = g * 64 + i;
            float4 w0 = wo4[d * 2 + 0];
            float4 w1 = wo4[d * 2 + 1];
            float dsum = w0.x * xq[0] + w0.y * xq[1] + w0.z * xq[2] + w0.w * xq[3] +
                         w1.x * xq[4] + w1.y * xq[5] + w1.z * xq[6] + w1.w * xq[7] +
                         obl[d];
            xr[i] -= dsum;
        }
        // next layer's codebook ds_writes happen after S3 (all VQ LDS reads complete);
        // resid touches only xqs/Wo/ob, disjoint from cnA/cnB/ccs/red.
    }

    // ---- epilogue: out0 = x - xr ----
    float* ocol = out0 + (size_t)b * Dx * Sx + s;
    #pragma unroll
    for (int i = 0; i < 64; i++) {
        float xv = xcol[(size_t)(g * 64 + i) * Sx];
        ocol[(size_t)(g * 64 + i) * Sx] = xv - xr[i];
    }

    // ---- loss reduce: wave -> block -> one atomic ----
    for (int off = 32; off; off >>= 1) lossp += __shfl_down(lossp, off);
    if (lane == 0) bred[wave] = lossp;
    __syncthreads();
    if (t == 0)
        atomicAdd(acc, (double)(bred[0] + bred[1] + bred[2] + bred[3]));
}

// ------------------------------- scalars from accumulator ----------------------------
__global__ void k_scalar(const double* __restrict__ acc,
                         float* __restrict__ commit, float* __restrict__ cbl) {
    if (threadIdx.x == 0) {
        float v = (float)(*acc / (double)((size_t)Bx * Ex * Sx));
        *commit = v;
        *cbl = v;
    }
}

extern "C" void kernel_launch(void* const* d_in, const int* in_sizes, int n_in,
                              void* d_out, int out_size, void* d_ws, size_t ws_size,
                              hipStream_t stream) {
    const float* x     = (const float*)d_in[0];
    const float* in_v  = (const float*)d_in[1];
    const float* in_g  = (const float*)d_in[2];
    const float* in_b  = (const float*)d_in[3];
    const float* out_v = (const float*)d_in[4];
    const float* out_g = (const float*)d_in[5];
    const float* out_b = (const float*)d_in[6];
    const float* cb    = (const float*)d_in[7];

    float* out = (float*)d_out;
    float* out0     = out;                        // [B,D,S]
    float* oidx     = out + 12288000;             // [B,L,S]
    float* ologits  = out + 12480000;             // [B*S,L,K]
    float* ocommit  = out + 209088000;
    float* ocbl     = out + 209088001;

    char* w = (char*)d_ws;
    float*  WiT   = (float*)(w);                  // L*D*E   = 32768 f
    float*  Wo    = (float*)(w + 131072);         // L*D*E   = 32768 f
    float*  cn    = (float*)(w + 262144);         // L*K*E   = 65536 f
    float*  cc    = (float*)(w + 524288);         // L*K     = 8192 f
    double* acc   = (double*)(w + 557056);        // 1 d

    k_wn_in<<<Lx * Ex, 64, 0, stream>>>(in_v, in_g, WiT);
    k_wn_out_cb<<<(Lx * Dx + Lx * Kx) / 256, 256, 0, stream>>>(out_v, out_g, cb,
                                                               Wo, cn, cc, acc);
    k_mega<<<BS / 32, 256, 0, stream>>>(x, WiT, in_b, Wo, out_b, cb, cn, cc,
                                        out0, oidx, ologits, acc);
    k_scalar<<<1, 64, 0, stream>>>(acc, ocommit, ocbl);
}

// Round 15
// 721.060 us; speedup vs baseline: 1.0257x; 1.0257x over previous
//
#include <hip/hip_runtime.h>

constexpr int Lx = 8;
constexpr int Bx = 16;
constexpr int Dx = 512;
constexpr int Sx = 1500;
constexpr int Ex = 8;
constexpr int Kx = 1024;
constexpr int BS = Bx * Sx;          // 24000
#define EPSF 1e-12f

// barrier that drains LDS ops only -- global stores stay in flight (m201 pattern)
__device__ __forceinline__ void lds_barrier() {
    asm volatile("s_waitcnt lgkmcnt(0)" ::: "memory");
    __builtin_amdgcn_s_barrier();
    asm volatile("" ::: "memory");
}

// -------- precompute: WiT[l][d][e] = (g*v/||v||)(e,d) transposed, norm over D --------
__global__ __launch_bounds__(64) void k_wn_in(const float* __restrict__ v,
                                              const float* __restrict__ g,
                                              float* __restrict__ WiT) {
    int row = blockIdx.x;            // l*E + e
    int l = row >> 3, e = row & 7;
    int lane = threadIdx.x;          // 0..63
    const float* vr = v + row * Dx;
    float s = 0.f;
    for (int j = lane; j < Dx; j += 64) { float t = vr[j]; s += t * t; }
    for (int off = 32; off; off >>= 1) s += __shfl_down(s, off);
    s = __shfl(s, 0);
    float scale = g[row] / sqrtf(s);
    for (int j = lane; j < Dx; j += 64)
        WiT[((size_t)l * Dx + j) * Ex + e] = vr[j] * scale;
}

// ------ precompute: Wo[l][d][e] (norm over E), cn = l2norm(cb), cc = sum(cn^2) -------
__global__ __launch_bounds__(256) void k_wn_out_cb(const float* __restrict__ ov,
                                                   const float* __restrict__ og,
                                                   const float* __restrict__ cb,
                                                   float* __restrict__ Wo,
                                                   float* __restrict__ cn,
                                                   float* __restrict__ cc,
                                                   double* __restrict__ acc) {
    int r = blockIdx.x * blockDim.x + threadIdx.x;
    if (r == 0) *acc = 0.0;
    if (r < Lx * Dx) {
        const float* vr = ov + r * Ex;
        float s = 0.f;
        #pragma unroll
        for (int e = 0; e < Ex; e++) s += vr[e] * vr[e];
        float sc = og[r] / sqrtf(s);
        #pragma unroll
        for (int e = 0; e < Ex; e++) Wo[r * Ex + e] = vr[e] * sc;
    } else {
        int q = r - Lx * Dx;
        if (q < Lx * Kx) {
            const float* vr = cb + q * Ex;
            float s = 0.f;
            #pragma unroll
            for (int e = 0; e < Ex; e++) s += vr[e] * vr[e];
            float n = fmaxf(sqrtf(s), EPSF);
            float s2 = 0.f, qv[Ex];
            #pragma unroll
            for (int e = 0; e < Ex; e++) { qv[e] = vr[e] / n; s2 += qv[e] * qv[e]; }
            #pragma unroll
            for (int e = 0; e < Ex; e++) cn[q * Ex + e] = qv[e];
            cc[q] = s2;
        }
    }
}

// ---------------------------- the fused 8-layer pipeline -----------------------------
// block = 256 threads = 32 columns x 8 d-groups. Each thread holds xr[d] for
// d = g*64 + i (i=0..63) of its column in registers across all layers.
// VQ: single 8-column pass per wave -- each LDS code-read amortized over 8 dots.
__global__ __launch_bounds__(256, 3) void k_mega(const float* __restrict__ x,
                                                 const float* __restrict__ WiT,
                                                 const float* __restrict__ ibias,
                                                 const float* __restrict__ Wo,
                                                 const float* __restrict__ obias,
                                                 const float* __restrict__ cb,
                                                 const float* __restrict__ cn,
                                                 const float* __restrict__ cc,
                                                 float* __restrict__ out0,
                                                 float* __restrict__ oidx,
                                                 float* __restrict__ logits,
                                                 double* __restrict__ acc) {
    __shared__ float4 cnA[Kx];            // 16 KB  codes e0..3 (contiguous: conflict-free)
    __shared__ float4 cnB[Kx];            // 16 KB  codes e4..7
    __shared__ float  ccs[Kx];            // 4 KB
    __shared__ float  red[8 * Ex * 32];   // 8 KB proj partials [g][e][col]
    __shared__ float  xprojs[Ex * 32];    // 1 KB  [e][col]
    __shared__ float  xqs[Ex * 32];       // 1 KB  [e][col]
    __shared__ float  bred[4];

    const int t = threadIdx.x;
    const int col = t & 31;
    const int g = t >> 5;
    const int wave = t >> 6, lane = t & 63;
    const int c = blockIdx.x * 32 + col;       // global column 0..23999
    const int b = c / Sx;
    const int s = c - b * Sx;
    const float* xcol = x + (size_t)b * Dx * Sx + s;

    float xr[64];
    #pragma unroll
    for (int i = 0; i < 64; i++) xr[i] = xcol[(size_t)(g * 64 + i) * Sx];

    float lossp = 0.f;

    for (int l = 0; l < Lx; l++) {
        // ---- issue codebook loads into regs (consumed after proj; hides latency) ----
        const float4* cn4 = (const float4*)(cn + (size_t)l * Kx * Ex);
        const float4* cc4 = (const float4*)(cc + l * Kx);
        float4 ra[4], rb[4], rc;
        #pragma unroll
        for (int q = 0; q < 4; q++) {
            ra[q] = cn4[(t + 256 * q) * 2];
            rb[q] = cn4[(t + 256 * q) * 2 + 1];
        }
        rc = cc4[t];

        // ---- proj partials: pacc[e] = sum_{d in mine} WiT[d][e] * xr[d] ----
        const float4* wt = (const float4*)(WiT + (size_t)l * Dx * Ex);
        float pacc[8] = {0, 0, 0, 0, 0, 0, 0, 0};
        #pragma unroll
        for (int i = 0; i < 64; i++) {
            int d = g * 64 + i;
            float4 w0 = wt[d * 2 + 0];
            float4 w1 = wt[d * 2 + 1];
            float v = xr[i];
            pacc[0] += w0.x * v; pacc[1] += w0.y * v;
            pacc[2] += w0.z * v; pacc[3] += w0.w * v;
            pacc[4] += w1.x * v; pacc[5] += w1.y * v;
            pacc[6] += w1.z * v; pacc[7] += w1.w * v;
        }
        #pragma unroll
        for (int e = 0; e < 8; e++) red[(g * 8 + e) * 32 + col] = pacc[e];

        // ---- write staged codebook to LDS (prev layer's VQ reads done: S3) ----
        #pragma unroll
        for (int q = 0; q < 4; q++) {
            cnA[t + 256 * q] = ra[q];
            cnB[t + 256 * q] = rb[q];
        }
        *(float4*)&ccs[t * 4] = rc;
        lds_barrier();                                     // S1: red + codebook ready

        // ---- finalize x_proj: thread (col, e=g) sums 8 partials + bias ----
        {
            float sum = 0.f;
            #pragma unroll
            for (int gg = 0; gg < 8; gg++) sum += red[(gg * 8 + g) * 32 + col];
            xprojs[g * 32 + col] = sum + ibias[l * Ex + g];
        }
        lds_barrier();                                     // S2: xprojs ready

        // ---- VQ: wave owns cols wave*8..wave*8+7; ONE 8-column pass ----
        {
            float xn2[8][8];                 // 2*xn (exact scaling; dot2 == 2*dot bitwise)
            float xc[8], best[8];
            int bk[8];
            float* lrow0 = logits + ((size_t)(blockIdx.x * 32 + wave * 8) * Lx + l) * Kx;
            #pragma unroll
            for (int c8 = 0; c8 < 8; c8++) {
                int mycol = wave * 8 + c8;
                float xp[8]; float xx2 = 0.f;
                #pragma unroll
                for (int e = 0; e < 8; e++) {
                    xp[e] = xprojs[e * 32 + mycol];
                    xx2 += xp[e] * xp[e];
                }
                float nrm = fmaxf(sqrtf(xx2), EPSF);
                float xx = 0.f;
                #pragma unroll
                for (int e = 0; e < 8; e++) {
                    float xnv = xp[e] / nrm;
                    xx += xnv * xnv;
                    xn2[c8][e] = 2.f * xnv;
                }
                xc[c8] = xx;
                best[c8] = -3.0e38f;
                bk[c8] = 0;
            }
            #pragma unroll 2
            for (int j = 0; j < 16; j++) {
                int k = j * 64 + lane;
                float4 a  = cnA[k];
                float4 b4 = cnB[k];
                float  cv = ccs[k];
                #pragma unroll
                for (int c8 = 0; c8 < 8; c8++) {
                    float dot2 = xn2[c8][0] * a.x  + xn2[c8][1] * a.y +
                                 xn2[c8][2] * a.z  + xn2[c8][3] * a.w +
                                 xn2[c8][4] * b4.x + xn2[c8][5] * b4.y +
                                 xn2[c8][6] * b4.z + xn2[c8][7] * b4.w;
                    float lg = -(xc[c8] - dot2 + cv);
                    lrow0[(size_t)c8 * (Lx * Kx) + k] = lg;
                    if (lg > best[c8]) { best[c8] = lg; bk[c8] = k; }
                }
            }
            #pragma unroll
            for (int c8 = 0; c8 < 8; c8++) {
                float bv = best[c8]; int bi = bk[c8];
                for (int off = 32; off; off >>= 1) {   // argmax, np tie-break
                    float ov = __shfl_xor(bv, off);
                    int   oi = __shfl_xor(bi, off);
                    if (ov > bv || (ov == bv && oi < bi)) { bv = ov; bi = oi; }
                }
                int mycol = wave * 8 + c8;
                int mc = blockIdx.x * 32 + mycol;
                int mb = mc / Sx, ms = mc - mb * Sx;
                if (lane == 0) oidx[((size_t)mb * Lx + l) * Sx + ms] = (float)bi;
                if (lane < 8) {
                    float q = cb[((size_t)l * Kx + bi) * Ex + lane];
                    xqs[lane * 32 + mycol] = q;
                    float dl = xprojs[lane * 32 + mycol] - q;
                    lossp += dl * dl;
                }
            }
        }
        lds_barrier();                                     // S3: xqs ready, VQ reads done

        // ---- residual update: xr[d] -= Wo[d][:] . xq + ob[d] ----
        float xq[8];
        #pragma unroll
        for (int e = 0; e < 8; e++) xq[e] = xqs[e * 32 + col];
        const float4* wo4 = (const float4*)(Wo + (size_t)l * Dx * Ex);
        const float* obl = obias + l * Dx;
        #pragma unroll
        for (int i = 0; i < 64; i++) {
            int d = g * 64 + i;
            float4 w0 = wo4[d * 2 + 0];
            float4 w1 = wo4[d * 2 + 1];
            float dsum = w0.x * xq[0] + w0.y * xq[1] + w0.z * xq[2] + w0.w * xq[3] +
                         w1.x * xq[4] + w1.y * xq[5] + w1.z * xq[6] + w1.w * xq[7] +
                         obl[d];
            xr[i] -= dsum;
        }
        // next layer's codebook ds_writes happen after S3 (all VQ LDS reads complete);
        // resid touches only xqs/Wo/ob, disjoint from cnA/cnB/ccs/red.
    }

    // ---- epilogue: out0 = x - xr ----
    float* ocol = out0 + (size_t)b * Dx * Sx + s;
    #pragma unroll
    for (int i = 0; i < 64; i++) {
        float xv = xcol[(size_t)(g * 64 + i) * Sx];
        ocol[(size_t)(g * 64 + i) * Sx] = xv - xr[i];
    }

    // ---- loss reduce: wave -> block -> one atomic ----
    for (int off = 32; off; off >>= 1) lossp += __shfl_down(lossp, off);
    if (lane == 0) bred[wave] = lossp;
    __syncthreads();
    if (t == 0)
        atomicAdd(acc, (double)(bred[0] + bred[1] + bred[2] + bred[3]));
}

// ------------------------------- scalars from accumulator ----------------------------
__global__ void k_scalar(const double* __restrict__ acc,
                         float* __restrict__ commit, float* __restrict__ cbl) {
    if (threadIdx.x == 0) {
        float v = (float)(*acc / (double)((size_t)Bx * Ex * Sx));
        *commit = v;
        *cbl = v;
    }
}

extern "C" void kernel_launch(void* const* d_in, const int* in_sizes, int n_in,
                              void* d_out, int out_size, void* d_ws, size_t ws_size,
                              hipStream_t stream) {
    const float* x     = (const float*)d_in[0];
    const float* in_v  = (const float*)d_in[1];
    const float* in_g  = (const float*)d_in[2];
    const float* in_b  = (const float*)d_in[3];
    const float* out_v = (const float*)d_in[4];
    const float* out_g = (const float*)d_in[5];
    const float* out_b = (const float*)d_in[6];
    const float* cb    = (const float*)d_in[7];

    float* out = (float*)d_out;
    float* out0     = out;                        // [B,D,S]
    float* oidx     = out + 12288000;             // [B,L,S]
    float* ologits  = out + 12480000;             // [B*S,L,K]
    float* ocommit  = out + 209088000;
    float* ocbl     = out + 209088001;

    char* w = (char*)d_ws;
    float*  WiT   = (float*)(w);                  // L*D*E   = 32768 f
    float*  Wo    = (float*)(w + 131072);         // L*D*E   = 32768 f
    float*  cn    = (float*)(w + 262144);         // L*K*E   = 65536 f
    float*  cc    = (float*)(w + 524288);         // L*K     = 8192 f
    double* acc   = (double*)(w + 557056);        // 1 d

    k_wn_in<<<Lx * Ex, 64, 0, stream>>>(in_v, in_g, WiT);
    k_wn_out_cb<<<(Lx * Dx + Lx * Kx) / 256, 256, 0, stream>>>(out_v, out_g, cb,
                                                               Wo, cn, cc, acc);
    k_mega<<<BS / 32, 256, 0, stream>>>(x, WiT, in_b, Wo, out_b, cb, cn, cc,
                                        out0, oidx, ologits, acc);
    k_scalar<<<1, 64, 0, stream>>>(acc, ocommit, ocbl);
}

// Round 16
// 636.096 us; speedup vs baseline: 1.1627x; 1.1336x over previous
//
#include <hip/hip_runtime.h>

constexpr int Lx = 8;
constexpr int Bx = 16;
constexpr int Dx = 512;
constexpr int Sx = 1500;
constexpr int Ex = 8;
constexpr int Kx = 1024;
constexpr int BS = Bx * Sx;          // 24000
constexpr int CB = 16;               // columns per block
#define EPSF 1e-12f

// barrier that drains LDS ops only -- global stores stay in flight
__device__ __forceinline__ void lds_barrier() {
    asm volatile("s_waitcnt lgkmcnt(0)" ::: "memory");
    __builtin_amdgcn_s_barrier();
    asm volatile("" ::: "memory");
}

// -------- precompute: WiT[l][d][e] = (g*v/||v||)(e,d) transposed, norm over D --------
__global__ __launch_bounds__(64) void k_wn_in(const float* __restrict__ v,
                                              const float* __restrict__ g,
                                              float* __restrict__ WiT) {
    int row = blockIdx.x;            // l*E + e
    int l = row >> 3, e = row & 7;
    int lane = threadIdx.x;          // 0..63
    const float* vr = v + row * Dx;
    float s = 0.f;
    for (int j = lane; j < Dx; j += 64) { float t = vr[j]; s += t * t; }
    for (int off = 32; off; off >>= 1) s += __shfl_down(s, off);
    s = __shfl(s, 0);
    float scale = g[row] / sqrtf(s);
    for (int j = lane; j < Dx; j += 64)
        WiT[((size_t)l * Dx + j) * Ex + e] = vr[j] * scale;
}

// ------ precompute: Wo[l][d][e] (norm over E), cn = l2norm(cb), cc = sum(cn^2) -------
__global__ __launch_bounds__(256) void k_wn_out_cb(const float* __restrict__ ov,
                                                   const float* __restrict__ og,
                                                   const float* __restrict__ cb,
                                                   float* __restrict__ Wo,
                                                   float* __restrict__ cn,
                                                   float* __restrict__ cc,
                                                   double* __restrict__ acc) {
    int r = blockIdx.x * blockDim.x + threadIdx.x;
    if (r == 0) *acc = 0.0;
    if (r < Lx * Dx) {
        const float* vr = ov + r * Ex;
        float s = 0.f;
        #pragma unroll
        for (int e = 0; e < Ex; e++) s += vr[e] * vr[e];
        float sc = og[r] / sqrtf(s);
        #pragma unroll
        for (int e = 0; e < Ex; e++) Wo[r * Ex + e] = vr[e] * sc;
    } else {
        int q = r - Lx * Dx;
        if (q < Lx * Kx) {
            const float* vr = cb + q * Ex;
            float s = 0.f;
            #pragma unroll
            for (int e = 0; e < Ex; e++) s += vr[e] * vr[e];
            float n = fmaxf(sqrtf(s), EPSF);
            float s2 = 0.f, qv[Ex];
            #pragma unroll
            for (int e = 0; e < Ex; e++) { qv[e] = vr[e] / n; s2 += qv[e] * qv[e]; }
            #pragma unroll
            for (int e = 0; e < Ex; e++) cn[q * Ex + e] = qv[e];
            cc[q] = s2;
        }
    }
}

// ---------------------------- the fused 8-layer pipeline -----------------------------
// block = 256 threads = 16 columns x 16 d-groups of 32. Each thread holds xr[32].
// 1500 blocks x 4 waves = 23.4 waves/CU grid ceiling; LDS 38 KB (red aliased into
// cnA) -> 4 blocks/CU -> 16 waves/CU. Wave owns 4 columns in VQ (single pass).
__global__ __launch_bounds__(256, 4) void k_mega(const float* __restrict__ x,
                                                 const float* __restrict__ WiT,
                                                 const float* __restrict__ ibias,
                                                 const float* __restrict__ Wo,
                                                 const float* __restrict__ obias,
                                                 const float* __restrict__ cb,
                                                 const float* __restrict__ cn,
                                                 const float* __restrict__ cc,
                                                 float* __restrict__ out0,
                                                 float* __restrict__ oidx,
                                                 float* __restrict__ logits,
                                                 double* __restrict__ acc) {
    __shared__ float4 cnA[Kx];            // 16 KB codes e0..3; first 8 KB double as red
    __shared__ float4 cnB[Kx];            // 16 KB codes e4..7
    __shared__ float  ccs[Kx];            // 4 KB
    __shared__ float  xprojs[Ex * CB];    // 512 B [e][col]
    __shared__ float  xqs[Ex * CB];       // 512 B [e][col]
    __shared__ float  bred[4];
    float* red = (float*)cnA;             // [16][8][16] = 2048 floats, dead after S2

    const int t = threadIdx.x;
    const int col = t & 15;
    const int g = t >> 4;                 // 0..15, d-slab of 32
    const int wave = t >> 6, lane = t & 63;
    const int c = blockIdx.x * CB + col;       // global column 0..23999
    const int b = c / Sx;
    const int s = c - b * Sx;
    const float* xcol = x + (size_t)b * Dx * Sx + s;

    float xr[32];
    #pragma unroll
    for (int i = 0; i < 32; i++) xr[i] = xcol[(size_t)(g * 32 + i) * Sx];

    float lossp = 0.f;

    for (int l = 0; l < Lx; l++) {
        // ---- issue codebook loads into regs (consumed after S2; latency hides) ----
        const float4* cn4 = (const float4*)(cn + (size_t)l * Kx * Ex);
        const float4* cc4 = (const float4*)(cc + (size_t)l * Kx);
        float4 ra[4], rb[4], rc;
        #pragma unroll
        for (int q = 0; q < 4; q++) {
            ra[q] = cn4[(t + 256 * q) * 2];
            rb[q] = cn4[(t + 256 * q) * 2 + 1];
        }
        rc = cc4[t];

        // ---- proj partials: pacc[e] = sum_{d in my slab} WiT[d][e] * xr[d] ----
        const float4* wt = (const float4*)(WiT + (size_t)l * Dx * Ex);
        float pacc[8] = {0, 0, 0, 0, 0, 0, 0, 0};
        #pragma unroll
        for (int i = 0; i < 32; i++) {
            int d = g * 32 + i;
            float4 w0 = wt[d * 2 + 0];
            float4 w1 = wt[d * 2 + 1];
            float v = xr[i];
            pacc[0] += w0.x * v; pacc[1] += w0.y * v;
            pacc[2] += w0.z * v; pacc[3] += w0.w * v;
            pacc[4] += w1.x * v; pacc[5] += w1.y * v;
            pacc[6] += w1.z * v; pacc[7] += w1.w * v;
        }
        #pragma unroll
        for (int e = 0; e < 8; e++) red[(g * 8 + e) * CB + col] = pacc[e];
        lds_barrier();                                     // S1: red ready

        // ---- finalize x_proj: threads t<128 (col=t&15, e=t>>4) sum 16 partials ----
        if (t < 128) {
            int e = t >> 4, cl = t & 15;
            float sum = 0.f;
            #pragma unroll
            for (int gg = 0; gg < 16; gg++) sum += red[(gg * 8 + e) * CB + cl];
            xprojs[e * CB + cl] = sum + ibias[l * Ex + e];
        }
        lds_barrier();                                     // S2: xprojs ready, red dead

        // ---- write staged codebook to LDS (overwrites red region) ----
        #pragma unroll
        for (int q = 0; q < 4; q++) {
            cnA[t + 256 * q] = ra[q];
            cnB[t + 256 * q] = rb[q];
        }
        *(float4*)&ccs[t * 4] = rc;
        lds_barrier();                                     // S2b: codebook ready

        // ---- VQ: wave owns cols wave*4..wave*4+3; single 4-col pass ----
        {
            float xn2[4][8];                 // 2*xn (exact; dot2 == 2*dot bitwise)
            float xc[4], best[4];
            int bk[4];
            float* lrow[4];
            #pragma unroll
            for (int c4 = 0; c4 < 4; c4++) {
                int mycol = wave * 4 + c4;
                int mc = blockIdx.x * CB + mycol;
                float xp[8]; float xx2 = 0.f;
                #pragma unroll
                for (int e = 0; e < 8; e++) {
                    xp[e] = xprojs[e * CB + mycol];
                    xx2 += xp[e] * xp[e];
                }
                float nrm = fmaxf(sqrtf(xx2), EPSF);
                float xx = 0.f;
                #pragma unroll
                for (int e = 0; e < 8; e++) {
                    float xnv = xp[e] / nrm;
                    xx += xnv * xnv;
                    xn2[c4][e] = 2.f * xnv;
                }
                xc[c4] = xx;
                best[c4] = -3.0e38f;
                bk[c4] = 0;
                lrow[c4] = logits + ((size_t)mc * Lx + l) * Kx;
            }
            #pragma unroll 2
            for (int j = 0; j < 16; j++) {
                int k = j * 64 + lane;
                float4 a  = cnA[k];
                float4 b4 = cnB[k];
                float  cv = ccs[k];
                #pragma unroll
                for (int c4 = 0; c4 < 4; c4++) {
                    float dot2 = xn2[c4][0] * a.x  + xn2[c4][1] * a.y +
                                 xn2[c4][2] * a.z  + xn2[c4][3] * a.w +
                                 xn2[c4][4] * b4.x + xn2[c4][5] * b4.y +
                                 xn2[c4][6] * b4.z + xn2[c4][7] * b4.w;
                    float lg = -(xc[c4] - dot2 + cv);
                    lrow[c4][k] = lg;
                    if (lg > best[c4]) { best[c4] = lg; bk[c4] = k; }
                }
            }
            #pragma unroll
            for (int c4 = 0; c4 < 4; c4++) {
                float bv = best[c4]; int bi = bk[c4];
                for (int off = 32; off; off >>= 1) {   // argmax, np tie-break
                    float ov = __shfl_xor(bv, off);
                    int   oi = __shfl_xor(bi, off);
                    if (ov > bv || (ov == bv && oi < bi)) { bv = ov; bi = oi; }
                }
                int mycol = wave * 4 + c4;
                int mc = blockIdx.x * CB + mycol;
                int mb = mc / Sx, ms = mc - mb * Sx;
                if (lane == 0) oidx[((size_t)mb * Lx + l) * Sx + ms] = (float)bi;
                if (lane < 8) {
                    float q = cb[((size_t)l * Kx + bi) * Ex + lane];
                    xqs[lane * CB + mycol] = q;
                    float dl = xprojs[lane * CB + mycol] - q;
                    lossp += dl * dl;
                }
            }
        }
        lds_barrier();                                     // S3: xqs ready, VQ reads done

        // ---- residual update: xr[d] -= Wo[d][:] . xq + ob[d] ----
        float xq[8];
        #pragma unroll
        for (int e = 0; e < 8; e++) xq[e] = xqs[e * CB + col];
        const float4* wo4 = (const float4*)(Wo + (size_t)l * Dx * Ex);
        const float* obl = obias + l * Dx;
        #pragma unroll
        for (int i = 0; i < 32; i++) {
            int d = g * 32 + i;
            float4 w0 = wo4[d * 2 + 0];
            float4 w1 = wo4[d * 2 + 1];
            float dsum = w0.x * xq[0] + w0.y * xq[1] + w0.z * xq[2] + w0.w * xq[3] +
                         w1.x * xq[4] + w1.y * xq[5] + w1.z * xq[6] + w1.w * xq[7] +
                         obl[d];
            xr[i] -= dsum;
        }
        // next layer's red writes hit cnA only after next S1-path (post-S3): safe.
    }

    // ---- epilogue: out0 = x - xr ----
    float* ocol = out0 + (size_t)b * Dx * Sx + s;
    #pragma unroll
    for (int i = 0; i < 32; i++) {
        float xv = xcol[(size_t)(g * 32 + i) * Sx];
        ocol[(size_t)(g * 32 + i) * Sx] = xv - xr[i];
    }

    // ---- loss reduce: wave -> block -> one atomic ----
    for (int off = 32; off; off >>= 1) lossp += __shfl_down(lossp, off);
    if (lane == 0) bred[wave] = lossp;
    __syncthreads();
    if (t == 0)
        atomicAdd(acc, (double)(bred[0] + bred[1] + bred[2] + bred[3]));
}

// ------------------------------- scalars from accumulator ----------------------------
__global__ void k_scalar(const double* __restrict__ acc,
                         float* __restrict__ commit, float* __restrict__ cbl) {
    if (threadIdx.x == 0) {
        float v = (float)(*acc / (double)((size_t)Bx * Ex * Sx));
        *commit = v;
        *cbl = v;
    }
}

extern "C" void kernel_launch(void* const* d_in, const int* in_sizes, int n_in,
                              void* d_out, int out_size, void* d_ws, size_t ws_size,
                              hipStream_t stream) {
    const float* x     = (const float*)d_in[0];
    const float* in_v  = (const float*)d_in[1];
    const float* in_g  = (const float*)d_in[2];
    const float* in_b  = (const float*)d_in[3];
    const float* out_v = (const float*)d_in[4];
    const float* out_g = (const float*)d_in[5];
    const float* out_b = (const float*)d_in[6];
    const float* cb    = (const float*)d_in[7];

    float* out = (float*)d_out;
    float* out0     = out;                        // [B,D,S]
    float* oidx     = out + 12288000;             // [B,L,S]
    float* ologits  = out + 12480000;             // [B*S,L,K]
    float* ocommit  = out + 209088000;
    float* ocbl     = out + 209088001;

    char* w = (char*)d_ws;
    float*  WiT   = (float*)(w);                  // L*D*E   = 32768 f
    float*  Wo    = (float*)(w + 131072);         // L*D*E   = 32768 f
    float*  cn    = (float*)(w + 262144);         // L*K*E   = 65536 f
    float*  cc    = (float*)(w + 524288);         // L*K     = 8192 f
    double* acc   = (double*)(w + 557056);        // 1 d

    k_wn_in<<<Lx * Ex, 64, 0, stream>>>(in_v, in_g, WiT);
    k_wn_out_cb<<<(Lx * Dx + Lx * Kx) / 256, 256, 0, stream>>>(out_v, out_g, cb,
                                                               Wo, cn, cc, acc);
    k_mega<<<BS / CB, 256, 0, stream>>>(x, WiT, in_b, Wo, out_b, cb, cn, cc,
                                        out0, oidx, ologits, acc);
    k_scalar<<<1, 64, 0, stream>>>(acc, ocommit, ocbl);
}

// Round 17
// 622.094 us; speedup vs baseline: 1.1889x; 1.0225x over previous
//
#include <hip/hip_runtime.h>

constexpr int Lx = 8;
constexpr int Bx = 16;
constexpr int Dx = 512;
constexpr int Sx = 1500;
constexpr int Ex = 8;
constexpr int Kx = 1024;
constexpr int BS = Bx * Sx;          // 24000
#define EPSF 1e-12f

// -------- precompute: WiT[l][d][e] = (g*v/||v||)(e,d) transposed, norm over D --------
__global__ __launch_bounds__(64) void k_wn_in(const float* __restrict__ v,
                                              const float* __restrict__ g,
                                              float* __restrict__ WiT) {
    int row = blockIdx.x;            // l*E + e
    int l = row >> 3, e = row & 7;
    int lane = threadIdx.x;          // 0..63
    const float* vr = v + row * Dx;
    float s = 0.f;
    for (int j = lane; j < Dx; j += 64) { float t = vr[j]; s += t * t; }
    for (int off = 32; off; off >>= 1) s += __shfl_down(s, off);
    s = __shfl(s, 0);
    float scale = g[row] / sqrtf(s);
    for (int j = lane; j < Dx; j += 64)
        WiT[((size_t)l * Dx + j) * Ex + e] = vr[j] * scale;
}

// ------ precompute: Wo[l][d][e] (norm over E), cn = l2norm(cb), cc = sum(cn^2) -------
__global__ __launch_bounds__(256) void k_wn_out_cb(const float* __restrict__ ov,
                                                   const float* __restrict__ og,
                                                   const float* __restrict__ cb,
                                                   float* __restrict__ Wo,
                                                   float* __restrict__ cn,
                                                   float* __restrict__ cc,
                                                   double* __restrict__ acc) {
    int r = blockIdx.x * blockDim.x + threadIdx.x;
    if (r == 0) *acc = 0.0;
    if (r < Lx * Dx) {
        const float* vr = ov + r * Ex;
        float s = 0.f;
        #pragma unroll
        for (int e = 0; e < Ex; e++) s += vr[e] * vr[e];
        float sc = og[r] / sqrtf(s);
        #pragma unroll
        for (int e = 0; e < Ex; e++) Wo[r * Ex + e] = vr[e] * sc;
    } else {
        int q = r - Lx * Dx;
        if (q < Lx * Kx) {
            const float* vr = cb + q * Ex;
            float s = 0.f;
            #pragma unroll
            for (int e = 0; e < Ex; e++) s += vr[e] * vr[e];
            float n = fmaxf(sqrtf(s), EPSF);
            float s2 = 0.f, qv[Ex];
            #pragma unroll
            for (int e = 0; e < Ex; e++) { qv[e] = vr[e] / n; s2 += qv[e] * qv[e]; }
            #pragma unroll
            for (int e = 0; e < Ex; e++) cn[q * Ex + e] = qv[e];
            cc[q] = s2;
        }
    }
}

// ---------------------------- the fused 8-layer pipeline -----------------------------
// block = 256 threads = 32 columns x 8 d-groups. Each thread holds xr[d] for
// d = g*64 + i (i=0..63) of its column in registers across all layers.
// Codebook staged per layer: global->regs issued BEFORE proj (latency hides under
// the proj FMA block), regs->LDS after proj, single barrier covers both.
__global__ __launch_bounds__(256, 3) void k_mega(const float* __restrict__ x,
                                                 const float* __restrict__ WiT,
                                                 const float* __restrict__ ibias,
                                                 const float* __restrict__ Wo,
                                                 const float* __restrict__ obias,
                                                 const float* __restrict__ cb,
                                                 const float* __restrict__ cn,
                                                 const float* __restrict__ cc,
                                                 float* __restrict__ out0,
                                                 float* __restrict__ oidx,
                                                 float* __restrict__ logits,
                                                 double* __restrict__ acc) {
    __shared__ float4 cnA[Kx];            // 16 KB  codes e0..3 (contiguous: conflict-free)
    __shared__ float4 cnB[Kx];            // 16 KB  codes e4..7
    __shared__ float  ccs[Kx];            // 4 KB
    __shared__ float  red[8 * Ex * 32];   // 8 KB proj partials [g][e][col]
    __shared__ float  xprojs[Ex * 32];    // 1 KB  [e][col]
    __shared__ float  xqs[Ex * 32];       // 1 KB  [e][col]
    __shared__ float  bred[4];

    const int t = threadIdx.x;
    const int col = t & 31;
    const int g = t >> 5;
    const int wave = t >> 6, lane = t & 63;
    const int c = blockIdx.x * 32 + col;       // global column 0..23999
    const int b = c / Sx;
    const int s = c - b * Sx;
    const float* xcol = x + (size_t)b * Dx * Sx + s;

    float xr[64];
    #pragma unroll
    for (int i = 0; i < 64; i++) xr[i] = xcol[(size_t)(g * 64 + i) * Sx];

    float lossp = 0.f;

    for (int l = 0; l < Lx; l++) {
        // ---- issue codebook loads into regs (consumed after proj; hides latency) ----
        const float4* cn4 = (const float4*)(cn + (size_t)l * Kx * Ex);
        const float4* cc4 = (const float4*)(cc + l * Kx);
        float4 ra[4], rb[4], rc;
        #pragma unroll
        for (int q = 0; q < 4; q++) {
            ra[q] = cn4[(t + 256 * q) * 2];
            rb[q] = cn4[(t + 256 * q) * 2 + 1];
        }
        rc = cc4[t];

        // ---- proj partials: pacc[e] = sum_{d in mine} WiT[d][e] * xr[d] ----
        const float4* wt = (const float4*)(WiT + (size_t)l * Dx * Ex);
        float pacc[8] = {0, 0, 0, 0, 0, 0, 0, 0};
        #pragma unroll
        for (int i = 0; i < 64; i++) {
            int d = g * 64 + i;
            float4 w0 = wt[d * 2 + 0];
            float4 w1 = wt[d * 2 + 1];
            float v = xr[i];
            pacc[0] += w0.x * v; pacc[1] += w0.y * v;
            pacc[2] += w0.z * v; pacc[3] += w0.w * v;
            pacc[4] += w1.x * v; pacc[5] += w1.y * v;
            pacc[6] += w1.z * v; pacc[7] += w1.w * v;
        }
        #pragma unroll
        for (int e = 0; e < 8; e++) red[(g * 8 + e) * 32 + col] = pacc[e];

        // ---- write staged codebook to LDS (prev layer's VQ reads done: S3) ----
        #pragma unroll
        for (int q = 0; q < 4; q++) {
            cnA[t + 256 * q] = ra[q];
            cnB[t + 256 * q] = rb[q];
        }
        *(float4*)&ccs[t * 4] = rc;
        __syncthreads();                                   // S1: red + codebook ready

        // ---- finalize x_proj: thread (col, e=g) sums 8 partials + bias ----
        {
            float sum = 0.f;
            #pragma unroll
            for (int gg = 0; gg < 8; gg++) sum += red[(gg * 8 + g) * 32 + col];
            xprojs[g * 32 + col] = sum + ibias[l * Ex + g];
        }
        __syncthreads();                                   // S2: xprojs ready

        // ---- VQ: wave owns cols wave*8..wave*8+7; two passes of 4 columns ----
        for (int pass = 0; pass < 2; pass++) {
            const int colbase = wave * 8 + pass * 4;
            float xn2[4][8];                 // 2*xn (exact scaling; dot2 == 2*dot bitwise)
            float xc[4], best[4];
            int bk[4];
            float* lrow[4];
            #pragma unroll
            for (int c4 = 0; c4 < 4; c4++) {
                int mycol = colbase + c4;
                int mc = blockIdx.x * 32 + mycol;
                float xp[8]; float xx2 = 0.f;
                #pragma unroll
                for (int e = 0; e < 8; e++) {
                    xp[e] = xprojs[e * 32 + mycol];
                    xx2 += xp[e] * xp[e];
                }
                float nrm = fmaxf(sqrtf(xx2), EPSF);
                float xx = 0.f;
                #pragma unroll
                for (int e = 0; e < 8; e++) {
                    float xnv = xp[e] / nrm;
                    xx += xnv * xnv;
                    xn2[c4][e] = 2.f * xnv;
                }
                xc[c4] = xx;
                best[c4] = -3.0e38f;
                bk[c4] = 0;
                lrow[c4] = logits + ((size_t)mc * Lx + l) * Kx;
            }
            #pragma unroll 2
            for (int j = 0; j < 16; j++) {
                int k = j * 64 + lane;
                float4 a  = cnA[k];
                float4 b4 = cnB[k];
                float  cv = ccs[k];
                #pragma unroll
                for (int c4 = 0; c4 < 4; c4++) {
                    float dot2 = xn2[c4][0] * a.x  + xn2[c4][1] * a.y +
                                 xn2[c4][2] * a.z  + xn2[c4][3] * a.w +
                                 xn2[c4][4] * b4.x + xn2[c4][5] * b4.y +
                                 xn2[c4][6] * b4.z + xn2[c4][7] * b4.w;
                    float lg = -(xc[c4] - dot2 + cv);
                    lrow[c4][k] = lg;
                    if (lg > best[c4]) { best[c4] = lg; bk[c4] = k; }
                }
            }
            #pragma unroll
            for (int c4 = 0; c4 < 4; c4++) {
                float bv = best[c4]; int bi = bk[c4];
                for (int off = 32; off; off >>= 1) {   // argmax, np tie-break
                    float ov = __shfl_xor(bv, off);
                    int   oi = __shfl_xor(bi, off);
                    if (ov > bv || (ov == bv && oi < bi)) { bv = ov; bi = oi; }
                }
                int mycol = colbase + c4;
                int mc = blockIdx.x * 32 + mycol;
                int mb = mc / Sx, ms = mc - mb * Sx;
                if (lane == 0) oidx[((size_t)mb * Lx + l) * Sx + ms] = (float)bi;
                if (lane < 8) {
                    float q = cb[((size_t)l * Kx + bi) * Ex + lane];
                    xqs[lane * 32 + mycol] = q;
                    float dl = xprojs[lane * 32 + mycol] - q;
                    lossp += dl * dl;
                }
            }
        }
        __syncthreads();                                   // S3: xqs ready, VQ reads done

        // ---- residual update: xr[d] -= Wo[d][:] . xq + ob[d] ----
        float xq[8];
        #pragma unroll
        for (int e = 0; e < 8; e++) xq[e] = xqs[e * 32 + col];
        const float4* wo4 = (const float4*)(Wo + (size_t)l * Dx * Ex);
        const float* obl = obias + l * Dx;
        #pragma unroll
        for (int i = 0; i < 64; i++) {
            int d = g * 64 + i;
            float4 w0 = wo4[d * 2 + 0];
            float4 w1 = wo4[d * 2 + 1];
            float dsum = w0.x * xq[0] + w0.y * xq[1] + w0.z * xq[2] + w0.w * xq[3] +
                         w1.x * xq[4] + w1.y * xq[5] + w1.z * xq[6] + w1.w * xq[7] +
                         obl[d];
            xr[i] -= dsum;
        }
        // next layer's codebook ds_writes happen after S3 (all VQ reads complete);
        // resid touches only xqs/Wo/ob, disjoint from cnA/cnB/ccs/red.
    }

    // ---- epilogue: out0 = x - xr ----
    float* ocol = out0 + (size_t)b * Dx * Sx + s;
    #pragma unroll
    for (int i = 0; i < 64; i++) {
        float xv = xcol[(size_t)(g * 64 + i) * Sx];
        ocol[(size_t)(g * 64 + i) * Sx] = xv - xr[i];
    }

    // ---- loss reduce: wave -> block -> one atomic ----
    for (int off = 32; off; off >>= 1) lossp += __shfl_down(lossp, off);
    if (lane == 0) bred[wave] = lossp;
    __syncthreads();
    if (t == 0)
        atomicAdd(acc, (double)(bred[0] + bred[1] + bred[2] + bred[3]));
}

// ------------------------------- scalars from accumulator ----------------------------
__global__ void k_scalar(const double* __restrict__ acc,
                         float* __restrict__ commit, float* __restrict__ cbl) {
    if (threadIdx.x == 0) {
        float v = (float)(*acc / (double)((size_t)Bx * Ex * Sx));
        *commit = v;
        *cbl = v;
    }
}

extern "C" void kernel_launch(void* const* d_in, const int* in_sizes, int n_in,
                              void* d_out, int out_size, void* d_ws, size_t ws_size,
                              hipStream_t stream) {
    const float* x     = (const float*)d_in[0];
    const float* in_v  = (const float*)d_in[1];
    const float* in_g  = (const float*)d_in[2];
    const float* in_b  = (const float*)d_in[3];
    const float* out_v = (const float*)d_in[4];
    const float* out_g = (const float*)d_in[5];
    const float* out_b = (const float*)d_in[6];
    const float* cb    = (const float*)d_in[7];

    float* out = (float*)d_out;
    float* out0     = out;                        // [B,D,S]
    float* oidx     = out + 12288000;             // [B,L,S]
    float* ologits  = out + 12480000;             // [B*S,L,K]
    float* ocommit  = out + 209088000;
    float* ocbl     = out + 209088001;

    char* w = (char*)d_ws;
    float*  WiT   = (float*)(w);                  // L*D*E   = 32768 f
    float*  Wo    = (float*)(w + 131072);         // L*D*E   = 32768 f
    float*  cn    = (float*)(w + 262144);         // L*K*E   = 65536 f
    float*  cc    = (float*)(w + 524288);         // L*K     = 8192 f
    double* acc   = (double*)(w + 557056);        // 1 d

    k_wn_in<<<Lx * Ex, 64, 0, stream>>>(in_v, in_g, WiT);
    k_wn_out_cb<<<(Lx * Dx + Lx * Kx) / 256, 256, 0, stream>>>(out_v, out_g, cb,
                                                               Wo, cn, cc, acc);
    k_mega<<<BS / 32, 256, 0, stream>>>(x, WiT, in_b, Wo, out_b, cb, cn, cc,
                                        out0, oidx, ologits, acc);
    k_scalar<<<1, 64, 0, stream>>>(acc, ocommit, ocbl);
}